// Round 1
// baseline (1103.676 us; speedup 1.0000x reference)
//
#include <hip/hip_runtime.h>

#define N_NODES 200000
#define N_EDGES 6400000

__global__ __launch_bounds__(256) void init_kernel(
    const float4* __restrict__ z_in,
    float4* __restrict__ z_cur,
    float4* __restrict__ x_out,
    float* __restrict__ agg)
{
    int n = blockIdx.x * blockDim.x + threadIdx.x;
    if (n < N_NODES) {
        float4 v = z_in[n];
        z_cur[n] = v;
        x_out[n] = v;   // second tuple output: x = original z
        agg[n] = 0.0f;
    }
}

__global__ __launch_bounds__(256) void edge_kernel(
    const float* __restrict__ z,
    const float* __restrict__ r,
    const float* __restrict__ r_hat,
    const int* __restrict__ src,
    const int* __restrict__ dst,
    const float* __restrict__ Wl,   // 12 weights for this layer
    const float* __restrict__ bl,   // 1 bias
    float* __restrict__ agg)
{
    int e = blockIdx.x * blockDim.x + threadIdx.x;
    if (e >= N_EDGES) return;

    // Wave-uniform weight loads -> compiler emits s_load (readonly + uniform addr)
    float w0 = Wl[0], w1 = Wl[1], w2 = Wl[2],  w3 = Wl[3];
    float w4 = Wl[4], w5 = Wl[5], w6 = Wl[6],  w7 = Wl[7];
    float w8 = Wl[8], w9 = Wl[9], w10 = Wl[10], w11 = Wl[11];
    float bias = bl[0];

    int s = src[e];
    int d = dst[e];
    float4 zs = ((const float4*)z)[s];
    float4 zd = ((const float4*)z)[d];
    float rv = r[e];
    const float* rh = r_hat + 3 * (size_t)e;
    float rh0 = rh[0], rh1 = rh[1], rh2 = rh[2];

    float msg = w0 * zs.x + w1 * zs.y + w2 * zs.z + w3 * zs.w
              + w4 * zd.x + w5 * zd.y + w6 * zd.z + w7 * zd.w
              + w8 * rv
              + w9 * rh0 + w10 * rh1 + w11 * rh2
              + bias;

    atomicAdd(&agg[d], msg);   // device-scope by default on CDNA
}

__global__ __launch_bounds__(256) void node_update(
    float4* __restrict__ z_cur,
    float* __restrict__ agg)
{
    int n = blockIdx.x * blockDim.x + threadIdx.x;
    if (n < N_NODES) {
        float a = agg[n];
        float4 v = z_cur[n];
        v.x += a; v.y += a; v.z += a; v.w += a;
        z_cur[n] = v;
        agg[n] = 0.0f;   // ready for next layer
    }
}

__global__ __launch_bounds__(256) void final_update(
    const float4* __restrict__ z_cur,
    const float* __restrict__ agg,
    float4* __restrict__ z_out)
{
    int n = blockIdx.x * blockDim.x + threadIdx.x;
    if (n < N_NODES) {
        float a = agg[n];
        float4 v = z_cur[n];
        v.x += a; v.y += a; v.z += a; v.w += a;
        z_out[n] = v;
    }
}

extern "C" void kernel_launch(void* const* d_in, const int* in_sizes, int n_in,
                              void* d_out, int out_size, void* d_ws, size_t ws_size,
                              hipStream_t stream)
{
    const float* z     = (const float*)d_in[0];   // [N,4]
    const float* r     = (const float*)d_in[1];   // [E,1]
    const float* r_hat = (const float*)d_in[2];   // [E,3]
    const float* W     = (const float*)d_in[3];   // [3,1,12]
    const float* b     = (const float*)d_in[4];   // [3,1]
    const int*   src   = (const int*)d_in[5];     // [E]
    const int*   dst   = (const int*)d_in[6];     // [E]
    float* out = (float*)d_out;                   // [z_final(N*4), x(N*4)]

    // Workspace layout: agg (N floats, 800000 B -> 16B-aligned) then z_cur (N*4 floats)
    float* agg   = (float*)d_ws;
    float* z_cur = agg + N_NODES;

    dim3 nblk((N_NODES + 255) / 256);
    dim3 eblk((N_EDGES + 255) / 256);

    init_kernel<<<nblk, 256, 0, stream>>>(
        (const float4*)z, (float4*)z_cur,
        (float4*)(out + 4 * (size_t)N_NODES), agg);

    for (int i = 0; i < 3; ++i) {
        edge_kernel<<<eblk, 256, 0, stream>>>(
            z_cur, r, r_hat, src, dst, W + 12 * i, b + i, agg);
        if (i < 2) {
            node_update<<<nblk, 256, 0, stream>>>((float4*)z_cur, agg);
        } else {
            final_update<<<nblk, 256, 0, stream>>>(
                (const float4*)z_cur, agg, (float4*)out);
        }
    }
}

// Round 2
// 1102.382 us; speedup vs baseline: 1.0012x; 1.0012x over previous
//
#include <hip/hip_runtime.h>

#define N_NODES 200000
#define N_EDGES 6400000

__global__ __launch_bounds__(256) void init_kernel(
    const float4* __restrict__ z_in,
    float4* __restrict__ z_cur,
    float4* __restrict__ x_out,
    float* __restrict__ agg)
{
    int n = blockIdx.x * blockDim.x + threadIdx.x;
    if (n < N_NODES) {
        float4 v = z_in[n];
        z_cur[n] = v;
        x_out[n] = v;   // second tuple output: x = original z
        agg[n] = 0.0f;
    }
}

__global__ __launch_bounds__(256) void edge_kernel(
    const float* __restrict__ z,
    const float* __restrict__ r,
    const float* __restrict__ r_hat,
    const int* __restrict__ src,
    const int* __restrict__ dst,
    const float* __restrict__ Wl,   // 12 weights for this layer
    const float* __restrict__ bl,   // 1 bias
    float* __restrict__ agg)
{
    int e = blockIdx.x * blockDim.x + threadIdx.x;
    if (e >= N_EDGES) return;

    // Wave-uniform weight loads -> s_load
    float w0 = Wl[0], w1 = Wl[1], w2 = Wl[2],  w3 = Wl[3];
    float w4 = Wl[4], w5 = Wl[5], w6 = Wl[6],  w7 = Wl[7];
    float w8 = Wl[8], w9 = Wl[9], w10 = Wl[10], w11 = Wl[11];
    float bias = bl[0];

    int s = src[e];
    int d = dst[e];
    float4 zs = ((const float4*)z)[s];
    float4 zd = ((const float4*)z)[d];
    float rv = r[e];
    const float* rh = r_hat + 3 * (size_t)e;
    float rh0 = rh[0], rh1 = rh[1], rh2 = rh[2];

    float msg = w0 * zs.x + w1 * zs.y + w2 * zs.z + w3 * zs.w
              + w4 * zd.x + w5 * zd.y + w6 * zd.z + w7 * zd.w
              + w8 * rv
              + w9 * rh0 + w10 * rh1 + w11 * rh2
              + bias;

    // HW fp32 atomic add, no return value -> global_atomic_add_f32,
    // fire-and-forget (no CAS loop, no round-trip wait).
    unsafeAtomicAdd(&agg[d], msg);
}

__global__ __launch_bounds__(256) void node_update(
    float4* __restrict__ z_cur,
    float* __restrict__ agg)
{
    int n = blockIdx.x * blockDim.x + threadIdx.x;
    if (n < N_NODES) {
        float a = agg[n];
        float4 v = z_cur[n];
        v.x += a; v.y += a; v.z += a; v.w += a;
        z_cur[n] = v;
        agg[n] = 0.0f;   // ready for next layer
    }
}

__global__ __launch_bounds__(256) void final_update(
    const float4* __restrict__ z_cur,
    const float* __restrict__ agg,
    float4* __restrict__ z_out)
{
    int n = blockIdx.x * blockDim.x + threadIdx.x;
    if (n < N_NODES) {
        float a = agg[n];
        float4 v = z_cur[n];
        v.x += a; v.y += a; v.z += a; v.w += a;
        z_out[n] = v;
    }
}

extern "C" void kernel_launch(void* const* d_in, const int* in_sizes, int n_in,
                              void* d_out, int out_size, void* d_ws, size_t ws_size,
                              hipStream_t stream)
{
    const float* z     = (const float*)d_in[0];   // [N,4]
    const float* r     = (const float*)d_in[1];   // [E,1]
    const float* r_hat = (const float*)d_in[2];   // [E,3]
    const float* W     = (const float*)d_in[3];   // [3,1,12]
    const float* b     = (const float*)d_in[4];   // [3,1]
    const int*   src   = (const int*)d_in[5];     // [E]
    const int*   dst   = (const int*)d_in[6];     // [E]
    float* out = (float*)d_out;                   // [z_final(N*4), x(N*4)]

    // Workspace layout: agg (N floats) then z_cur (N*4 floats)
    float* agg   = (float*)d_ws;
    float* z_cur = agg + N_NODES;

    dim3 nblk((N_NODES + 255) / 256);
    dim3 eblk((N_EDGES + 255) / 256);

    init_kernel<<<nblk, 256, 0, stream>>>(
        (const float4*)z, (float4*)z_cur,
        (float4*)(out + 4 * (size_t)N_NODES), agg);

    for (int i = 0; i < 3; ++i) {
        edge_kernel<<<eblk, 256, 0, stream>>>(
            z_cur, r, r_hat, src, dst, W + 12 * i, b + i, agg);
        if (i < 2) {
            node_update<<<nblk, 256, 0, stream>>>((float4*)z_cur, agg);
        } else {
            final_update<<<nblk, 256, 0, stream>>>(
                (const float4*)z_cur, agg, (float4*)out);
        }
    }
}

// Round 3
// 467.758 us; speedup vs baseline: 2.3595x; 2.3567x over previous
//
#include <hip/hip_runtime.h>

#define N_NODES 200000
#define N_EDGES 6400000
#define K_BUCKETS 256
#define BUCKET 784          // 256*784 = 200704 >= 200000; max dstLocal < 1024
#define NSB 800             // scatter blocks
#define CHUNK 8000          // NSB*CHUNK == N_EDGES exactly

// ---------------- fast path kernels ----------------

__global__ __launch_bounds__(256) void copy_x(const float4* __restrict__ z,
                                              float4* __restrict__ x_out)
{
    int n = blockIdx.x * 256 + threadIdx.x;
    if (n < N_NODES) x_out[n] = z[n];
}

__global__ __launch_bounds__(256) void hist_kernel(const int* __restrict__ dst,
                                                   int* __restrict__ counts)
{
    __shared__ int cnt[K_BUCKETS];
    int tid = threadIdx.x, sb = blockIdx.x;
    cnt[tid] = 0;
    __syncthreads();
    int e0 = sb * CHUNK;
    for (int i = tid; i < CHUNK; i += 256) {
        int d = dst[e0 + i];
        atomicAdd(&cnt[d / BUCKET], 1);      // LDS atomic
    }
    __syncthreads();
    counts[sb * K_BUCKETS + tid] = cnt[tid];
}

__global__ __launch_bounds__(256) void scan_kernel(const int* __restrict__ counts,
                                                   int* __restrict__ base,
                                                   int* __restrict__ bstart)
{
    __shared__ int tot[K_BUCKETS];
    __shared__ int sc[K_BUCKETS + 1];
    int k = threadIdx.x;
    int t = 0;
    for (int sb = 0; sb < NSB; ++sb) t += counts[sb * K_BUCKETS + k];
    tot[k] = t;
    __syncthreads();
    if (k == 0) {
        int run = 0;
        for (int i = 0; i < K_BUCKETS; ++i) { sc[i] = run; run += tot[i]; }
        sc[K_BUCKETS] = run;
    }
    __syncthreads();
    bstart[k] = sc[k];
    if (k == 0) bstart[K_BUCKETS] = sc[K_BUCKETS];
    int run = sc[k];
    for (int sb = 0; sb < NSB; ++sb) {
        base[sb * K_BUCKETS + k] = run;
        run += counts[sb * K_BUCKETS + k];
    }
}

// One pass over edge data: bucketize + precompute per-layer static scalar c_i.
__global__ __launch_bounds__(256) void scatter_kernel(
    const int* __restrict__ src, const int* __restrict__ dst,
    const float* __restrict__ r, const float* __restrict__ r_hat,
    const float* __restrict__ W, const float* __restrict__ b,
    const int* __restrict__ base, float4* __restrict__ payload)
{
    __shared__ int cur[K_BUCKETS];
    int tid = threadIdx.x, sb = blockIdx.x;
    cur[tid] = base[sb * K_BUCKETS + tid];
    __syncthreads();

    float w8_0 = W[8],  w9_0 = W[9],  w10_0 = W[10], w11_0 = W[11], b0 = b[0];
    float w8_1 = W[20], w9_1 = W[21], w10_1 = W[22], w11_1 = W[23], b1 = b[1];
    float w8_2 = W[32], w9_2 = W[33], w10_2 = W[34], w11_2 = W[35], b2 = b[2];

    int e0 = sb * CHUNK;
    for (int i = tid; i < CHUNK; i += 256) {
        int e = e0 + i;
        int d = dst[e];
        int k = d / BUCKET;
        int dl = d - k * BUCKET;
        int pos = atomicAdd(&cur[k], 1);     // LDS atomic, returns slot
        int s = src[e];
        float rv = r[e];
        size_t he = 3 * (size_t)e;
        float h0 = r_hat[he], h1 = r_hat[he + 1], h2 = r_hat[he + 2];
        float4 rec;
        rec.x = __int_as_float((s << 10) | dl);
        rec.y = w8_0 * rv + w9_0 * h0 + w10_0 * h1 + w11_0 * h2 + b0;
        rec.z = w8_1 * rv + w9_1 * h0 + w10_1 * h1 + w11_1 * h2 + b1;
        rec.w = w8_2 * rv + w9_2 * h0 + w10_2 * h1 + w11_2 * h2 + b2;
        payload[pos] = rec;
    }
}

// One block per bucket (exclusive ownership): LDS aggregation, plain stores out.
__global__ __launch_bounds__(1024) void layer_kernel(
    const float4* __restrict__ z_prev,
    const float4* __restrict__ payload,
    const int* __restrict__ bstart,
    const float* __restrict__ Wl,   // 12 weights of this layer
    int layer,
    float4* __restrict__ z_next)
{
    __shared__ float4 zsl[BUCKET];
    __shared__ float aggsl[BUCKET];
    int tid = threadIdx.x;
    int k = blockIdx.x;
    int nbase = k * BUCKET;
    int nn = min(BUCKET, N_NODES - nbase);

    for (int i = tid; i < nn; i += 1024) { zsl[i] = z_prev[nbase + i]; aggsl[i] = 0.0f; }
    __syncthreads();

    float ws0 = Wl[0], ws1 = Wl[1], ws2 = Wl[2], ws3 = Wl[3];
    float wd0 = Wl[4], wd1 = Wl[5], wd2 = Wl[6], wd3 = Wl[7];

    int estart = bstart[k], eend = bstart[k + 1];
    for (int i = estart + tid; i < eend; i += 1024) {
        float4 rec = payload[i];
        int pack = __float_as_int(rec.x);
        int s  = pack >> 10;
        int dl = pack & 1023;
        float c = (layer == 0) ? rec.y : (layer == 1 ? rec.z : rec.w);
        float4 zs = z_prev[s];
        float4 zd = zsl[dl];
        float msg = ws0 * zs.x + ws1 * zs.y + ws2 * zs.z + ws3 * zs.w
                  + wd0 * zd.x + wd1 * zd.y + wd2 * zd.z + wd3 * zd.w + c;
        atomicAdd(&aggsl[dl], msg);          // LDS atomic (ds_add_f32)
    }
    __syncthreads();

    for (int i = tid; i < nn; i += 1024) {
        float a = aggsl[i];
        float4 v = zsl[i];
        v.x += a; v.y += a; v.z += a; v.w += a;
        z_next[nbase + i] = v;
    }
}

// ---------------- fallback (round-2) kernels ----------------

__global__ __launch_bounds__(256) void init_kernel(
    const float4* __restrict__ z_in, float4* __restrict__ z_cur,
    float4* __restrict__ x_out, float* __restrict__ agg)
{
    int n = blockIdx.x * blockDim.x + threadIdx.x;
    if (n < N_NODES) {
        float4 v = z_in[n];
        z_cur[n] = v; x_out[n] = v; agg[n] = 0.0f;
    }
}

__global__ __launch_bounds__(256) void edge_kernel(
    const float* __restrict__ z, const float* __restrict__ r,
    const float* __restrict__ r_hat, const int* __restrict__ src,
    const int* __restrict__ dst, const float* __restrict__ Wl,
    const float* __restrict__ bl, float* __restrict__ agg)
{
    int e = blockIdx.x * blockDim.x + threadIdx.x;
    if (e >= N_EDGES) return;
    float w0 = Wl[0], w1 = Wl[1], w2 = Wl[2], w3 = Wl[3];
    float w4 = Wl[4], w5 = Wl[5], w6 = Wl[6], w7 = Wl[7];
    float w8 = Wl[8], w9 = Wl[9], w10 = Wl[10], w11 = Wl[11];
    float bias = bl[0];
    int s = src[e], d = dst[e];
    float4 zs = ((const float4*)z)[s];
    float4 zd = ((const float4*)z)[d];
    float rv = r[e];
    const float* rh = r_hat + 3 * (size_t)e;
    float msg = w0*zs.x + w1*zs.y + w2*zs.z + w3*zs.w
              + w4*zd.x + w5*zd.y + w6*zd.z + w7*zd.w
              + w8*rv + w9*rh[0] + w10*rh[1] + w11*rh[2] + bias;
    unsafeAtomicAdd(&agg[d], msg);
}

__global__ __launch_bounds__(256) void node_update(float4* __restrict__ z_cur,
                                                   float* __restrict__ agg)
{
    int n = blockIdx.x * blockDim.x + threadIdx.x;
    if (n < N_NODES) {
        float a = agg[n]; float4 v = z_cur[n];
        v.x += a; v.y += a; v.z += a; v.w += a;
        z_cur[n] = v; agg[n] = 0.0f;
    }
}

__global__ __launch_bounds__(256) void final_update(const float4* __restrict__ z_cur,
                                                    const float* __restrict__ agg,
                                                    float4* __restrict__ z_out)
{
    int n = blockIdx.x * blockDim.x + threadIdx.x;
    if (n < N_NODES) {
        float a = agg[n]; float4 v = z_cur[n];
        v.x += a; v.y += a; v.z += a; v.w += a;
        z_out[n] = v;
    }
}

// ---------------- launch ----------------

extern "C" void kernel_launch(void* const* d_in, const int* in_sizes, int n_in,
                              void* d_out, int out_size, void* d_ws, size_t ws_size,
                              hipStream_t stream)
{
    const float* z     = (const float*)d_in[0];
    const float* r     = (const float*)d_in[1];
    const float* r_hat = (const float*)d_in[2];
    const float* W     = (const float*)d_in[3];
    const float* b     = (const float*)d_in[4];
    const int*   src   = (const int*)d_in[5];
    const int*   dst   = (const int*)d_in[6];
    float* out = (float*)d_out;

    // workspace layout
    char* ws = (char*)d_ws;
    size_t off = 0;
    float4* payload = (float4*)(ws + off); off += (size_t)N_EDGES * 16;
    int* counts = (int*)(ws + off); off += (size_t)NSB * K_BUCKETS * 4;
    int* base   = (int*)(ws + off); off += (size_t)NSB * K_BUCKETS * 4;
    int* bstart = (int*)(ws + off); off += (size_t)(K_BUCKETS + 1) * 4;
    off = (off + 15) & ~(size_t)15;
    float* bufA = (float*)(ws + off); off += (size_t)N_NODES * 4 * 4;
    float* bufB = (float*)(ws + off); off += (size_t)N_NODES * 4 * 4;
    size_t required = off;

    dim3 nblk((N_NODES + 255) / 256);

    if (ws_size >= required) {
        // -------- fast path: atomic-free bucketed aggregation --------
        copy_x<<<nblk, 256, 0, stream>>>((const float4*)z,
                                         (float4*)(out + 4 * (size_t)N_NODES));
        hist_kernel<<<NSB, 256, 0, stream>>>(dst, counts);
        scan_kernel<<<1, 256, 0, stream>>>(counts, base, bstart);
        scatter_kernel<<<NSB, 256, 0, stream>>>(src, dst, r, r_hat, W, b, base, payload);

        layer_kernel<<<K_BUCKETS, 1024, 0, stream>>>(
            (const float4*)z, payload, bstart, W + 0, 0, (float4*)bufA);
        layer_kernel<<<K_BUCKETS, 1024, 0, stream>>>(
            (const float4*)bufA, payload, bstart, W + 12, 1, (float4*)bufB);
        layer_kernel<<<K_BUCKETS, 1024, 0, stream>>>(
            (const float4*)bufB, payload, bstart, W + 24, 2, (float4*)out);
    } else {
        // -------- fallback: round-2 path --------
        float* agg   = (float*)d_ws;
        float* z_cur = agg + N_NODES;
        dim3 eblk((N_EDGES + 255) / 256);
        init_kernel<<<nblk, 256, 0, stream>>>(
            (const float4*)z, (float4*)z_cur,
            (float4*)(out + 4 * (size_t)N_NODES), agg);
        for (int i = 0; i < 3; ++i) {
            edge_kernel<<<eblk, 256, 0, stream>>>(
                z_cur, r, r_hat, src, dst, W + 12 * i, b + i, agg);
            if (i < 2)
                node_update<<<nblk, 256, 0, stream>>>((float4*)z_cur, agg);
            else
                final_update<<<nblk, 256, 0, stream>>>(
                    (const float4*)z_cur, agg, (float4*)out);
        }
    }
}